// Round 9
// baseline (153.982 us; speedup 1.0000x reference)
//
#include <hip/hip_runtime.h>
#include <math.h>
#include <stdint.h>

// Video Swin shifted-window attention.
// Round 9: two-kernel pipeline for 2 blocks/CU.
//  K1 swin_qkattn: per (window, head-pair) block, 512 thr, 73.7KB LDS
//     -> 2 blocks/CU co-resident (barrier-independent overlap).
//     Phase 2 = R8's verified 32x32 P-in-register path (8 tasks = 8 waves).
//     O -> ws as bf16 (coalesced via LDS restage).
//  K2 swin_proj: y = O @ Wproj^T + b, 256 thr, 16KB LDS, streaming GEMM.
//  Fallback (ws too small): R6 fused kernel (proven 137us).

#define LOG2E   1.4426950408889634f
#define MASKNEG (-144.26950408889634f)   // -100 * LOG2E

typedef __attribute__((ext_vector_type(8)))  short    bf16x8;
typedef __attribute__((ext_vector_type(4)))  float    f32x4;
typedef __attribute__((ext_vector_type(16))) float    f32x16;
typedef __attribute__((ext_vector_type(4)))  unsigned uint32x4;

__device__ __forceinline__ unsigned short cvt1(float f) {
    __bf16 h = (__bf16)f;
    return __builtin_bit_cast(unsigned short, h);
}
__device__ __forceinline__ unsigned cvt2(float lo, float hi) {
    return (unsigned)cvt1(lo) | ((unsigned)cvt1(hi) << 16);
}
__device__ __forceinline__ void pswap(unsigned &a, unsigned &b) {
    asm volatile("v_permlane32_swap_b32 %0, %1" : "+v"(a), "+v"(b));
}
__device__ __forceinline__ int tok_code(int t) {
    int pd = t / 49;
    int r  = t - pd * 49;
    int ph = r / 7;
    int pw = r - ph * 7;
    return (pd >= 1 ? 1 : 0) | (ph >= 4 ? 2 : 0) | (pw >= 4 ? 4 : 0);
}
__device__ __forceinline__ float mterm(unsigned pk, int sh, unsigned ci, unsigned cls) {
    return ((((pk >> sh) & 255u) ^ ci) & cls) ? MASKNEG : 0.f;
}
// swizzles: stride-128 tiles (16B chunks, row&7 + row>>3 entropy)
__device__ __forceinline__ int swz2(int row, int col) {
    return row * 128 + ((((col >> 3) ^ (row & 7) ^ ((row >> 3) & 3)) & 15) << 3) + (col & 7);
}
// stride-64 tiles (8 chunks)
__device__ __forceinline__ int swz64(int row, int col) {
    return row * 64 + ((((col >> 3) ^ (row & 7)) & 7) << 3) + (col & 7);
}
// fallback (R6) swizzles
__device__ __forceinline__ int swzA(int row, int col) {
    return row * 128 + (((col >> 3) ^ (row & 7)) << 3) + (col & 7);
}
__device__ __forceinline__ int vswz(int row, int col) {
    return row * 128 + ((((col >> 3) ^ (row & 7) ^ ((row >> 2) & 3)) & 15) << 3) + (col & 7);
}

// ============ pipeline prep: weights -> bf16, gathered 32x32 bias table ============
__global__ void pipe_prep(const float* __restrict__ qkv_w,
                          const float* __restrict__ proj_w,
                          const float* __restrict__ rpb_table,
                          const int*   __restrict__ rel_index,
                          unsigned short* __restrict__ wqkv,
                          unsigned short* __restrict__ wproj,
                          float* __restrict__ bm) {
    int tid = blockIdx.x * blockDim.x + threadIdx.x;
    int stride = gridDim.x * blockDim.x;
    for (int i = tid; i < 384 * 128; i += stride) wqkv[i]  = cvt1(qkv_w[i]);
    for (int i = tid; i < 128 * 128; i += stride) wproj[i] = cvt1(proj_w[i]);
    // bm[cls8][h4][it4][jt4][q4][hi2][il32][e4] f32, *LOG2E, mask folded, j>=98 -inf
    for (int idx = tid; idx < 524288; idx += stride) {
        int e  = idx & 3;
        int il = (idx >> 2) & 31;
        int hi = (idx >> 7) & 1;
        int q  = (idx >> 8) & 3;
        int jt = (idx >> 10) & 3;
        int it = (idx >> 12) & 3;
        int h  = (idx >> 14) & 3;
        int cl = (idx >> 16);
        int i = it * 32 + il;
        int j = jt * 32 + q * 8 + hi * 4 + e;
        float v;
        if (j >= 98) v = -INFINITY;
        else if (i >= 98) v = 0.f;
        else {
            float bias = rpb_table[rel_index[i * 98 + j] * 4 + h];
            bool  msk  = (((unsigned)tok_code(i) ^ (unsigned)tok_code(j)) & (unsigned)cl) != 0;
            v = bias * LOG2E + (msk ? MASKNEG : 0.f);
        }
        bm[idx] = v;
    }
}

// ============ K1: QKV + attention per (window, head-pair) ============
__global__ __launch_bounds__(512, 4)
void swin_qkattn(const float* __restrict__ x,
                 const float* __restrict__ qkv_b,
                 const unsigned short* __restrict__ wqkv,
                 const float* __restrict__ bm,
                 unsigned* __restrict__ O_ws)    // [2048*98][64] dwords (=128 bf16/tok)
{
    extern __shared__ unsigned short lds[];
    unsigned short* x_lds  = lds;            // [112][128] swz2; O (cols 0..63) after P2
    unsigned short* q_lds  = lds + 14336;    // [112][64] swz64
    unsigned short* k_lds  = lds + 21504;    // [112][64]
    unsigned short* vT_lds = lds + 28672;    // [64][128] swz2 (cols 112..127 zero)
    // total 36864 ush = 73728 B

    const int bid  = blockIdx.x;
    const int b    = bid >> 1;     // window
    const int g    = bid & 1;      // head pair (heads 2g, 2g+1)
    const int tid  = threadIdx.x;
    const int wv   = tid >> 6;     // 0..7
    const int lane = tid & 63;
    const int l4   = lane >> 4;
    const int lc   = lane & 15;

    // zero vT pad cols 112..127 (64 rows x 16 cols = 1024 ush; 2/thread)
    {
        int idx2 = tid * 2;
        int row  = idx2 >> 4;      // 0..63
        int c    = 112 + (idx2 & 15);
        *(unsigned*)(vT_lds + swz2(row, c)) = 0u;
    }
    // stage x (rows 98..111 zero)
    {
        const float* xb = x + (size_t)b * 12544;
        for (int idx = tid; idx < 3584; idx += 512) {
            int tok = idx >> 5;
            int c   = (idx & 31) << 2;
            float4 v;
            if (tok < 98) v = *(const float4*)(xb + tok * 128 + c);
            else { v.x = 0.f; v.y = 0.f; v.z = 0.f; v.w = 0.f; }
            uint2 hv; hv.x = cvt2(v.x, v.y); hv.y = cvt2(v.z, v.w);
            *(uint2*)(x_lds + swz2(tok, c)) = hv;
        }
    }
    __syncthreads();

    // ---- Phase 1: q,k (64 chs each) + vT for this head pair ----
    {
        const bool isq = (wv < 4);
        const int  lt  = wv & 3;                       // local ch tile
        const int  wbase = (isq ? 0 : 128) + g * 64 + lt * 16;
        bf16x8 wf[4];
        const unsigned short* wrow = wqkv + (wbase + lc) * 128;
#pragma unroll
        for (int kt = 0; kt < 4; ++kt) wf[kt] = *(const bf16x8*)(wrow + kt * 32 + l4 * 8);
        f32x4 bias;
#pragma unroll
        for (int r = 0; r < 4; ++r) bias[r] = qkv_b[wbase + l4 * 4 + r];
        const float qs = 0.17677669529663689f * LOG2E;
        unsigned short* dst = isq ? q_lds : k_lds;
#pragma unroll
        for (int t = 0; t < 7; ++t) {
            bf16x8 xf[4];
#pragma unroll
            for (int kt = 0; kt < 4; ++kt)
                xf[kt] = *(bf16x8*)(x_lds + swz2(t * 16 + lc, kt * 32 + l4 * 8));
            f32x4 acc = bias;
#pragma unroll
            for (int kt = 0; kt < 4; ++kt)
                acc = __builtin_amdgcn_mfma_f32_16x16x32_bf16(wf[kt], xf[kt], acc, 0, 0, 0);
            int tok = t * 16 + lc;
            uint2 hv;
            if (isq) { hv.x = cvt2(acc[0] * qs, acc[1] * qs); hv.y = cvt2(acc[2] * qs, acc[3] * qs); }
            else     { hv.x = cvt2(acc[0], acc[1]);           hv.y = cvt2(acc[2], acc[3]); }
            *(uint2*)(dst + swz64(tok, lt * 16 + l4 * 4)) = hv;
        }
        // v: wave pair owns local d-tile vd, t-halves by wv&1
        const int vd = (wv >> 1) * 16;                 // 0..48
        bf16x8 wf2[4];
        const unsigned short* wrow2 = wqkv + (256 + g * 64 + vd + lc) * 128;
#pragma unroll
        for (int kt = 0; kt < 4; ++kt) wf2[kt] = *(const bf16x8*)(wrow2 + kt * 32 + l4 * 8);
        f32x4 bias2;
#pragma unroll
        for (int r = 0; r < 4; ++r) bias2[r] = qkv_b[256 + g * 64 + vd + l4 * 4 + r];
        const int t0 = (wv & 1) ? 4 : 0, t1 = (wv & 1) ? 7 : 4;
        for (int t = t0; t < t1; ++t) {
            bf16x8 xf[4];
#pragma unroll
            for (int kt = 0; kt < 4; ++kt)
                xf[kt] = *(bf16x8*)(x_lds + swz2(t * 16 + lc, kt * 32 + l4 * 8));
            f32x4 acc = bias2;
#pragma unroll
            for (int kt = 0; kt < 4; ++kt)
                acc = __builtin_amdgcn_mfma_f32_16x16x32_bf16(wf2[kt], xf[kt], acc, 0, 0, 0);
            int tok = t * 16 + lc;
            const int rb = vd + l4 * 4;
            vT_lds[swz2(rb + 0, tok)] = cvt1(acc[0]);
            vT_lds[swz2(rb + 1, tok)] = cvt1(acc[1]);
            vT_lds[swz2(rb + 2, tok)] = cvt1(acc[2]);
            vT_lds[swz2(rb + 3, tok)] = cvt1(acc[3]);
        }
    }
    __syncthreads();

    // ---- Phase 2: 32x32 attention, 8 tasks = 8 waves (R8 machinery) ----
    {
        const int wi  = b & 255;
        const unsigned cls =
            ((wi >> 6) == 3 ? 1u : 0u) | (((wi >> 3) & 7) == 7 ? 2u : 0u) | ((wi & 7) == 7 ? 4u : 0u);
        const int il  = lane & 31;
        const int hi2 = lane >> 5;
        const int hl    = wv >> 2;          // local head 0/1
        const int itile = wv & 3;
        const int hg    = g * 2 + hl;       // global head
        const int i_tok = itile * 32 + il;

        f32x16 S[4];
        const float* tb = bm + (((size_t)(cls * 4 + hg) * 4 + itile) * 4) * 1024 + hi2 * 128 + il * 4;
#pragma unroll
        for (int jt = 0; jt < 4; ++jt)
#pragma unroll
            for (int q = 0; q < 4; ++q) {
                f32x4 v = *(const f32x4*)(tb + (jt * 8 + q * 2) * 128);
                S[jt][q * 4 + 0] = v[0]; S[jt][q * 4 + 1] = v[1];
                S[jt][q * 4 + 2] = v[2]; S[jt][q * 4 + 3] = v[3];
            }

        bf16x8 qfa = *(bf16x8*)(q_lds + swz64(i_tok, hl * 32 + hi2 * 8));
        bf16x8 qfb = *(bf16x8*)(q_lds + swz64(i_tok, hl * 32 + 16 + hi2 * 8));
#pragma unroll
        for (int jt = 0; jt < 4; ++jt) {
            bf16x8 ka = *(bf16x8*)(k_lds + swz64(jt * 32 + il, hl * 32 + hi2 * 8));
            bf16x8 kb = *(bf16x8*)(k_lds + swz64(jt * 32 + il, hl * 32 + 16 + hi2 * 8));
            S[jt] = __builtin_amdgcn_mfma_f32_32x32x16_bf16(ka, qfa, S[jt], 0, 0, 0);
            S[jt] = __builtin_amdgcn_mfma_f32_32x32x16_bf16(kb, qfb, S[jt], 0, 0, 0);
        }

        float m = S[0][0];
#pragma unroll
        for (int jt = 0; jt < 4; ++jt)
#pragma unroll
            for (int r = 0; r < 16; ++r)
                if (!(jt == 0 && r == 0)) m = fmaxf(m, S[jt][r]);
        m = fmaxf(m, __shfl_xor(m, 32));

        float l = 0.f;
        unsigned dw[4][8];
#pragma unroll
        for (int jt = 0; jt < 4; ++jt)
#pragma unroll
            for (int d = 0; d < 8; ++d) {
                float p0 = exp2f(S[jt][2 * d]     - m);
                float p1 = exp2f(S[jt][2 * d + 1] - m);
                l += p0 + p1;
                dw[jt][d] = cvt2(p0, p1);
            }
        l += __shfl_xor(l, 32);

#pragma unroll
        for (int jt = 0; jt < 4; ++jt) {
            pswap(dw[jt][0], dw[jt][2]);
            pswap(dw[jt][1], dw[jt][3]);
            pswap(dw[jt][4], dw[jt][6]);
            pswap(dw[jt][5], dw[jt][7]);
        }

        f32x16 O = {0.f,0.f,0.f,0.f,0.f,0.f,0.f,0.f,0.f,0.f,0.f,0.f,0.f,0.f,0.f,0.f};
#pragma unroll
        for (int jt = 0; jt < 4; ++jt)
#pragma unroll
            for (int p = 0; p < 2; ++p) {
                bf16x8 vf = *(bf16x8*)(vT_lds + swz2(hl * 32 + il, jt * 32 + p * 16 + hi2 * 8));
                uint32x4 pu = { dw[jt][p * 4 + 0], dw[jt][p * 4 + 1],
                                dw[jt][p * 4 + 2], dw[jt][p * 4 + 3] };
                O = __builtin_amdgcn_mfma_f32_32x32x16_bf16(
                        vf, __builtin_bit_cast(bf16x8, pu), O, 0, 0, 0);
            }

        const float inv = 1.0f / l;
#pragma unroll
        for (int rr = 0; rr < 8; ++rr) {
            int r = rr * 2;
            int d = (r & 3) + 8 * (r >> 2) + 4 * hi2;
            *(unsigned*)(x_lds + swz2(i_tok, hl * 32 + d)) = cvt2(O[r] * inv, O[r + 1] * inv);
        }
    }
    __syncthreads();

    // ---- copy-out O (x_lds cols 0..63) -> O_ws, coalesced ----
    {
        for (int idx = tid; idx < 3136; idx += 512) {   // 98 tok x 32 dwords
            int tok = idx >> 5;
            int c   = (idx & 31) * 2;
            unsigned v = *(unsigned*)(x_lds + swz2(tok, c));
            O_ws[((size_t)b * 98 + tok) * 64 + g * 32 + (idx & 31)] = v;
        }
    }
}

// ============ K2: proj GEMM ============
__global__ __launch_bounds__(256)
void swin_proj(const unsigned short* __restrict__ O_ws,
               const unsigned short* __restrict__ wproj,
               const float* __restrict__ proj_b,
               float* __restrict__ out)
{
    __shared__ unsigned short ot[8192];   // [64][128] swz2
    const int tid  = threadIdx.x;
    const int wv   = tid >> 6;
    const int lane = tid & 63;
    const int l4   = lane >> 4;
    const int lc   = lane & 15;
    const size_t T0 = (size_t)blockIdx.x * 64;

    for (int idx = tid; idx < 1024; idx += 256) {
        int tok_l = idx >> 4;
        int c     = (idx & 15) << 3;
        bf16x8 v = *(const bf16x8*)(O_ws + (T0 + tok_l) * 128 + c);
        *(bf16x8*)(ot + swz2(tok_l, c)) = v;
    }
    __syncthreads();

#pragma unroll
    for (int pass = 0; pass < 2; ++pass) {
        const int ct = wv + pass * 4;
        bf16x8 pw[4];
#pragma unroll
        for (int kt = 0; kt < 4; ++kt)
            pw[kt] = *(const bf16x8*)(wproj + (ct * 16 + lc) * 128 + kt * 32 + l4 * 8);
        f32x4 pbias;
#pragma unroll
        for (int r = 0; r < 4; ++r) pbias[r] = proj_b[ct * 16 + l4 * 4 + r];
#pragma unroll
        for (int t = 0; t < 4; ++t) {
            f32x4 acc = pbias;
#pragma unroll
            for (int kt = 0; kt < 4; ++kt) {
                bf16x8 of = *(bf16x8*)(ot + swz2(t * 16 + lc, kt * 32 + l4 * 8));
                acc = __builtin_amdgcn_mfma_f32_16x16x32_bf16(pw[kt], of, acc, 0, 0, 0);
            }
            float4 st; st.x = acc[0]; st.y = acc[1]; st.z = acc[2]; st.w = acc[3];
            *(float4*)(out + (T0 + t * 16 + lc) * 128 + ct * 16 + l4 * 4) = st;
        }
    }
}

// ============ fallback: R6 fused kernel (proven) ============
template<bool BIG>
__global__ void fb_prep(const float* __restrict__ qkv_w,
                        const float* __restrict__ proj_w,
                        const float* __restrict__ rpb_table,
                        const int*   __restrict__ rel_index,
                        unsigned short* __restrict__ wqkv,
                        unsigned short* __restrict__ wproj,
                        void* __restrict__ btab) {
    int tid = blockIdx.x * blockDim.x + threadIdx.x;
    int stride = gridDim.x * blockDim.x;
    for (int i = tid; i < 384 * 128; i += stride) wqkv[i]  = cvt1(qkv_w[i]);
    for (int i = tid; i < 128 * 128; i += stride) wproj[i] = cvt1(proj_w[i]);
    if constexpr (BIG) {
        float* bm = (float*)btab;
        for (int idx = tid; idx < 32 * 112 * 112; idx += stride) {
            int ch = idx / 12544; int r = idx - ch * 12544;
            int i  = r / 112;     int j = r - i * 112;
            int cls = ch >> 2, h = ch & 3;
            float v;
            if (i < 98) {
                if (j < 98) {
                    float bias = rpb_table[rel_index[i * 98 + j] * 4 + h];
                    bool  msk  = (((unsigned)tok_code(i) ^ (unsigned)tok_code(j)) & (unsigned)cls) != 0;
                    v = bias * LOG2E + (msk ? MASKNEG : 0.f);
                } else v = -INFINITY;
            } else v = 0.f;
            bm[idx] = v;
        }
    } else {
        unsigned short* biasL = (unsigned short*)btab;
        for (int idx = tid; idx < 4 * 112 * 112; idx += stride) {
            int h = idx / 12544; int r = idx - h * 12544;
            int i = r / 112;     int j = r - i * 112;
            float v;
            if (i < 98) v = (j < 98) ? rpb_table[rel_index[i * 98 + j] * 4 + h] * LOG2E
                                     : -INFINITY;
            else v = 0.f;
            biasL[idx] = cvt1(v);
        }
    }
}

template<bool BIG>
__global__ __launch_bounds__(1024)
void fb_main(const float* __restrict__ x,
             const float* __restrict__ qkv_b,
             const float* __restrict__ proj_b,
             const unsigned short* __restrict__ wqkv,
             const unsigned short* __restrict__ wproj,
             const void* __restrict__ btab,
             float* __restrict__ out)
{
    extern __shared__ unsigned short lds[];
    unsigned short* q_lds  = lds;
    unsigned short* k_lds  = lds + 14336;
    unsigned short* vT_lds = lds + 28672;
    unsigned short* xo_lds = lds + 45056;
    unsigned short* p_lds  = lds + 59392;

    const int b    = blockIdx.x;
    const int tid  = threadIdx.x;
    const int wv   = tid >> 6;
    const int lane = tid & 63;
    const int l4   = lane >> 4;
    const int lc   = lane & 15;

    {
        int idx2 = tid * 2;
        int row  = idx2 >> 4;
        int c    = 112 + (idx2 & 15);
        *(unsigned*)(vT_lds + vswz(row, c)) = 0u;
    }
    {
        const float* xb = x + (size_t)b * 12544;
        for (int idx = tid; idx < 3584; idx += 1024) {
            int tok = idx >> 5;
            int c   = (idx & 31) << 2;
            float4 v;
            if (tok < 98) v = *(const float4*)(xb + tok * 128 + c);
            else { v.x = 0.f; v.y = 0.f; v.z = 0.f; v.w = 0.f; }
            uint2 hv; hv.x = cvt2(v.x, v.y); hv.y = cvt2(v.z, v.w);
            *(uint2*)(xo_lds + swzA(tok, c)) = hv;
        }
    }
    __syncthreads();
    {
        const int ct = wv;
        bf16x8 wf[4];
        f32x4  bias;
        const unsigned short* wrow = wqkv + (ct * 16 + lc) * 128;
#pragma unroll
        for (int kt = 0; kt < 4; ++kt) wf[kt] = *(const bf16x8*)(wrow + kt * 32 + l4 * 8);
#pragma unroll
        for (int r = 0; r < 4; ++r) bias[r] = qkv_b[ct * 16 + l4 * 4 + r];
        const bool  isq = (ct < 8);
        const float qs  = 0.17677669529663689f * LOG2E;
#pragma unroll
        for (int t = 0; t < 7; ++t) {
            bf16x8 xf[4];
#pragma unroll
            for (int kt = 0; kt < 4; ++kt)
                xf[kt] = *(bf16x8*)(xo_lds + swzA(t * 16 + lc, kt * 32 + l4 * 8));
            f32x4 acc = bias;
#pragma unroll
            for (int kt = 0; kt < 4; ++kt)
                acc = __builtin_amdgcn_mfma_f32_16x16x32_bf16(wf[kt], xf[kt], acc, 0, 0, 0);
            int tok = t * 16 + lc;
            if (isq) {
                uint2 hv; hv.x = cvt2(acc[0] * qs, acc[1] * qs); hv.y = cvt2(acc[2] * qs, acc[3] * qs);
                *(uint2*)(q_lds + swzA(tok, ct * 16 + l4 * 4)) = hv;
            } else {
                uint2 hv; hv.x = cvt2(acc[0], acc[1]); hv.y = cvt2(acc[2], acc[3]);
                *(uint2*)(k_lds + swzA(tok, (ct - 8) * 16 + l4 * 4)) = hv;
            }
        }
        const int vd = (wv >> 1) * 16;
        bf16x8 wf2[4];
        const unsigned short* wrow2 = wqkv + (256 + vd + lc) * 128;
#pragma unroll
        for (int kt = 0; kt < 4; ++kt) wf2[kt] = *(const bf16x8*)(wrow2 + kt * 32 + l4 * 8);
        f32x4 bias2;
#pragma unroll
        for (int r = 0; r < 4; ++r) bias2[r] = qkv_b[256 + vd + l4 * 4 + r];
        const int t0 = (wv & 1) ? 4 : 0, t1 = (wv & 1) ? 7 : 4;
        for (int t = t0; t < t1; ++t) {
            bf16x8 xf[4];
#pragma unroll
            for (int kt = 0; kt < 4; ++kt)
                xf[kt] = *(bf16x8*)(xo_lds + swzA(t * 16 + lc, kt * 32 + l4 * 8));
            f32x4 acc = bias2;
#pragma unroll
            for (int kt = 0; kt < 4; ++kt)
                acc = __builtin_amdgcn_mfma_f32_16x16x32_bf16(wf2[kt], xf[kt], acc, 0, 0, 0);
            int tok = t * 16 + lc;
            const int rb = vd + l4 * 4;
            vT_lds[vswz(rb + 0, tok)] = cvt1(acc[0]);
            vT_lds[vswz(rb + 1, tok)] = cvt1(acc[1]);
            vT_lds[vswz(rb + 2, tok)] = cvt1(acc[2]);
            vT_lds[vswz(rb + 3, tok)] = cvt1(acc[3]);
        }
    }
    __syncthreads();

    const int wi  = b & 255;
    const unsigned cls =
        ((wi >> 6) == 3 ? 1u : 0u) | (((wi >> 3) & 7) == 7 ? 2u : 0u) | ((wi & 7) == 7 ? 4u : 0u);

    unsigned jcp[7];
    if constexpr (!BIG) {
#pragma unroll
        for (int jt = 0; jt < 7; ++jt) {
            int jb = jt * 16 + l4 * 4;
            unsigned p = 0;
#pragma unroll
            for (int r = 0; r < 4; ++r) p |= (unsigned)tok_code(jb + r < 98 ? jb + r : 0) << (8 * r);
            jcp[jt] = p;
        }
    }
    unsigned short* myP = p_lds + wv * 1280;

    for (int pass = 0; pass < 2; ++pass) {
        int task = wv + (pass << 4);
        if (task >= 28) break;
        int h  = task / 7;
        int it = task - h * 7;
        const int i_tok = it * 16 + lc;
        const bf16x8 qfrag = *(bf16x8*)(q_lds + swzA(i_tok, h * 32 + l4 * 8));

        f32x4 cvec[7];
        if constexpr (BIG) {
            const float* bmrow = (const float*)btab + ((size_t)((int)cls * 4 + h) * 112 + i_tok) * 112;
#pragma unroll
            for (int jt = 0; jt < 7; ++jt)
                cvec[jt] = *(const f32x4*)(bmrow + jt * 16 + l4 * 4);
        } else {
            const unsigned short* brow = (const unsigned short*)btab + (h * 112 + i_tok) * 112;
            const unsigned ci = (unsigned)tok_code(i_tok < 98 ? i_tok : 0);
            ushort4 bb[7];
#pragma unroll
            for (int jt = 0; jt < 7; ++jt)
                bb[jt] = *(const ushort4*)(brow + jt * 16 + l4 * 4);
#pragma unroll
            for (int jt = 0; jt < 7; ++jt) {
                cvec[jt][0] = __builtin_bit_cast(float, (unsigned)bb[jt].x << 16) + mterm(jcp[jt], 0,  ci, cls);
                cvec[jt][1] = __builtin_bit_cast(float, (unsigned)bb[jt].y << 16) + mterm(jcp[jt], 8,  ci, cls);
                cvec[jt][2] = __builtin_bit_cast(float, (unsigned)bb[jt].z << 16) + mterm(jcp[jt], 16, ci, cls);
                cvec[jt][3] = __builtin_bit_cast(float, (unsigned)bb[jt].w << 16) + mterm(jcp[jt], 24, ci, cls);
            }
        }

        f32x4 s[7];
#pragma unroll
        for (int jt = 0; jt < 7; ++jt) {
            bf16x8 kfrag = *(bf16x8*)(k_lds + swzA(jt * 16 + lc, h * 32 + l4 * 8));
            s[jt] = __builtin_amdgcn_mfma_f32_16x16x32_bf16(kfrag, qfrag, cvec[jt], 0, 0, 0);
        }

        float m = -INFINITY;
#pragma unroll
        for (int jt = 0; jt < 7; ++jt)
            m = fmaxf(m, fmaxf(fmaxf(s[jt][0], s[jt][1]), fmaxf(s[jt][2], s[jt][3])));
        m = fmaxf(m, __shfl_xor(m, 16));
        m = fmaxf(m, __shfl_xor(m, 32));

        float lsum = 0.f;
        f32x4 o0 = {0.f, 0.f, 0.f, 0.f}, o1 = {0.f, 0.f, 0.f, 0.f};
#pragma unroll
        for (int jt4 = 0; jt4 < 4; ++jt4) {
            unsigned short* pb = myP + (jt4 & 1) * 640;
#pragma unroll
            for (int sub = 0; sub < 2; ++sub) {
                int jt = jt4 * 2 + sub;
                uint2 pv;
                if (jt < 7) {
                    float p0 = exp2f(s[jt][0] - m);
                    float p1 = exp2f(s[jt][1] - m);
                    float p2 = exp2f(s[jt][2] - m);
                    float p3 = exp2f(s[jt][3] - m);
                    lsum += (p0 + p1) + (p2 + p3);
                    pv.x = cvt2(p0, p1); pv.y = cvt2(p2, p3);
                } else {
                    pv.x = 0u; pv.y = 0u;
                }
                *(uint2*)(pb + lc * 40 + sub * 16 + l4 * 4) = pv;
            }
            bf16x8 pfrag = *(bf16x8*)(pb + lc * 40 + l4 * 8);
            bf16x8 va = *(bf16x8*)(vT_lds + vswz(h * 32 + lc,      jt4 * 32 + l4 * 8));
            bf16x8 vb = *(bf16x8*)(vT_lds + vswz(h * 32 + 16 + lc, jt4 * 32 + l4 * 8));
            o0 = __builtin_amdgcn_mfma_f32_16x16x32_bf16(va, pfrag, o0, 0, 0, 0);
            o1 = __builtin_amdgcn_mfma_f32_16x16x32_bf16(vb, pfrag, o1, 0, 0, 0);
        }
        lsum += __shfl_xor(lsum, 16);
        lsum += __shfl_xor(lsum, 32);

        float inv = 1.0f / lsum;
        uint2 h0, h1;
        h0.x = cvt2(o0[0] * inv, o0[1] * inv); h0.y = cvt2(o0[2] * inv, o0[3] * inv);
        h1.x = cvt2(o1[0] * inv, o1[1] * inv); h1.y = cvt2(o1[2] * inv, o1[3] * inv);
        *(uint2*)(xo_lds + swzA(i_tok, h * 32 + l4 * 4)) = h0;
        *(uint2*)(xo_lds + swzA(i_tok, h * 32 + 16 + l4 * 4)) = h1;
    }
    __syncthreads();
    {
        const int ct = wv >> 1;
        bf16x8 pw[4];
#pragma unroll
        for (int kt = 0; kt < 4; ++kt)
            pw[kt] = *(const bf16x8*)(wproj + (ct * 16 + lc) * 128 + kt * 32 + l4 * 8);
        f32x4 pbias;
#pragma unroll
        for (int r = 0; r < 4; ++r) pbias[r] = proj_b[ct * 16 + l4 * 4 + r];

        float* ob = out + (size_t)b * 12544;
        const int t0 = (wv & 1) ? 4 : 0, t1 = (wv & 1) ? 7 : 4;
        for (int t = t0; t < t1; ++t) {
            f32x4 acc = pbias;
#pragma unroll
            for (int kt = 0; kt < 4; ++kt) {
                bf16x8 of = *(bf16x8*)(xo_lds + swzA(t * 16 + lc, kt * 32 + l4 * 8));
                acc = __builtin_amdgcn_mfma_f32_16x16x32_bf16(pw[kt], of, acc, 0, 0, 0);
            }
            int tok = t * 16 + lc;
            if (tok < 98) {
                float4 st; st.x = acc[0]; st.y = acc[1]; st.z = acc[2]; st.w = acc[3];
                *(float4*)(ob + tok * 128 + ct * 16 + l4 * 4) = st;
            }
        }
    }
}

extern "C" void kernel_launch(void* const* d_in, const int* in_sizes, int n_in,
                              void* d_out, int out_size, void* d_ws, size_t ws_size,
                              hipStream_t stream) {
    const float* x       = (const float*)d_in[0];
    const float* qkv_w   = (const float*)d_in[1];
    const float* qkv_b   = (const float*)d_in[2];
    const float* rpb_tab = (const float*)d_in[3];
    const float* proj_w  = (const float*)d_in[4];
    const float* proj_b  = (const float*)d_in[5];
    const int*   rel_idx = (const int*)d_in[6];
    // d_in[7] (mask) unused: reproduced analytically into the tables.

    unsigned short* wqkv  = (unsigned short*)d_ws;                   // 98304 B
    unsigned short* wproj = (unsigned short*)((char*)d_ws + 98304);  // 32768 B
    void*           btab  = (void*)((char*)d_ws + 131072);           // bias table
    float*          out   = (float*)d_out;

    const size_t PIPE_WS = 131072u + 2097152u + (size_t)200704 * 128 * 2;  // 53,608,448
    if (ws_size >= PIPE_WS) {
        float*    bm   = (float*)btab;                                // 2MB gathered
        unsigned* O_ws = (unsigned*)((char*)d_ws + 131072 + 2097152); // 51MB
        hipLaunchKernelGGL(pipe_prep, dim3(512), dim3(256), 0, stream,
                           qkv_w, proj_w, rpb_tab, rel_idx, wqkv, wproj, bm);
        (void)hipFuncSetAttribute((const void*)swin_qkattn,
                                  hipFuncAttributeMaxDynamicSharedMemorySize, 73728);
        hipLaunchKernelGGL(swin_qkattn, dim3(4096), dim3(512), 73728, stream,
                           x, qkv_b, wqkv, bm, O_ws);
        hipLaunchKernelGGL(swin_proj, dim3(3136), dim3(256), 0, stream,
                           (const unsigned short*)O_ws, wproj, proj_b, out);
    } else if (ws_size >= (size_t)(131072 + 32 * 112 * 112 * 4)) {
        hipLaunchKernelGGL((fb_prep<true>), dim3(512), dim3(256), 0, stream,
                           qkv_w, proj_w, rpb_tab, rel_idx, wqkv, wproj, btab);
        (void)hipFuncSetAttribute((const void*)(fb_main<true>),
                                  hipFuncAttributeMaxDynamicSharedMemorySize, 159744);
        hipLaunchKernelGGL((fb_main<true>), dim3(2048), dim3(1024), 159744, stream,
                           x, qkv_b, proj_b, wqkv, wproj, btab, out);
    } else {
        hipLaunchKernelGGL((fb_prep<false>), dim3(512), dim3(256), 0, stream,
                           qkv_w, proj_w, rpb_tab, rel_idx, wqkv, wproj, btab);
        (void)hipFuncSetAttribute((const void*)(fb_main<false>),
                                  hipFuncAttributeMaxDynamicSharedMemorySize, 159744);
        hipLaunchKernelGGL((fb_main<false>), dim3(2048), dim3(1024), 159744, stream,
                           x, qkv_b, proj_b, wqkv, wproj, btab, out);
    }
}